// Round 8
// baseline (292.805 us; speedup 1.0000x reference)
//
#include <hip/hip_runtime.h>

// MQA forward on MI355X (gfx950), bf16 MFMA path.
// B=2, S=2048, D_MODEL=2048, H=16, HEAD_DIM=128 (MQA: K/V shared across heads).
// R2: T2 XOR-swizzle in flash (bank conflicts 9.1e7 -> 0; 290 -> 191 us).
// R4: 2-phase dbuf staging (vmcnt(8)): -2%. Kept.
// R5: direct-global K/V frags: -87% (uncoalesced gather). REVERTED.
// R6: softmax-lite (deferred l-sum, T13 defer-max): 187 -> 167 us.
// R7: swapped-operand flash (lane owns one q-row): 167 -> 139 us.
// R8: v_cvt_pk_bf16_f32 for P/O packing (96 -> 8 VALU ops/iter on P-pack);
//     exp2-direct: log2(e) folded into Q pre-scale, threshold 8 -> 11.54.

typedef __attribute__((ext_vector_type(8))) short short8;
typedef __attribute__((ext_vector_type(4))) float f32x4;
typedef __attribute__((ext_vector_type(4))) unsigned int uint4v;

__device__ __forceinline__ unsigned short f2bf(float f) {
  unsigned int u = __float_as_uint(f);
  u += 0x7FFF + ((u >> 16) & 1);   // RNE
  return (unsigned short)(u >> 16);
}

// pack 2 f32 -> 2 bf16 in one op (gfx950 v_cvt_pk_bf16_f32, RNE)
__device__ __forceinline__ unsigned int pkc(float a, float b) {
  unsigned int r;
  asm("v_cvt_pk_bf16_f32 %0, %1, %2" : "=v"(r) : "v"(a), "v"(b));
  return r;
}

// async global->LDS 16B: dst must be wave-uniform (HW adds lane*16)
__device__ __forceinline__ void gll16(const void* g, void* lds) {
  __builtin_amdgcn_global_load_lds(
      (const __attribute__((address_space(1))) unsigned int*)g,
      (__attribute__((address_space(3))) unsigned int*)lds, 16, 0, 0);
}

// ---------------- elementwise f32 -> bf16 ----------------
__global__ __launch_bounds__(256) void cvtk(const float* __restrict__ in,
                                            unsigned short* __restrict__ out, int n4) {
  int i = blockIdx.x * blockDim.x + threadIdx.x;
  int stride = gridDim.x * blockDim.x;
  for (; i < n4; i += stride) {
    float4 v = reinterpret_cast<const float4*>(in)[i];
    ushort4 o;
    o.x = f2bf(v.x); o.y = f2bf(v.y); o.z = f2bf(v.z); o.w = f2bf(v.w);
    reinterpret_cast<ushort4*>(out)[i] = o;
  }
}

// ------- transpose + convert (paired): W[K][N] f32 -> Wt[N][K] bf16, z selects -------
__global__ __launch_bounds__(256) void tcvt2(const float* __restrict__ W0, const float* __restrict__ W1,
                                             unsigned short* __restrict__ D0, unsigned short* __restrict__ D1,
                                             int K, int N) {
  const float* W = blockIdx.z ? W1 : W0;
  unsigned short* Wt = blockIdx.z ? D1 : D0;
  __shared__ float tile[32][33];
  int n0 = blockIdx.x * 32, k0 = blockIdx.y * 32;
  int tx = threadIdx.x, ty = threadIdx.y;
  #pragma unroll
  for (int i = 0; i < 32; i += 8)
    tile[ty + i][tx] = W[(size_t)(k0 + ty + i) * N + n0 + tx];
  __syncthreads();
  #pragma unroll
  for (int i = 0; i < 32; i += 8)
    Wt[(size_t)(n0 + ty + i) * K + k0 + tx] = f2bf(tile[tx][ty + i]);
}

// ---------------- GEMM: C = A[M][K] @ Bt[N][K]^T + bias ----------------
// 128x128 tile, BK=64, 256 threads = 4 waves (2x2 of 64x64), m97-style.
// MODE 1: f32 out C[M][N] (+b0)
// MODE 3: fused QKV epilogue (N=2304):
//   col<2048   -> qb[row][col] bf16 = (acc+b0)*cmul
//   col<2176   -> kbuf[row][col-2048] bf16 (+b1)
//   else       -> vt[b][col-2176][s] bf16 (+b2), transposed
template <int MODE>
__global__ __launch_bounds__(256)
void gemm_nt(const unsigned short* __restrict__ A, const unsigned short* __restrict__ Bt,
             const float* __restrict__ b0, const float* __restrict__ b1,
             const float* __restrict__ b2,
             void* __restrict__ C, unsigned short* __restrict__ C2,
             unsigned short* __restrict__ C3, int M, int N, int K, float cmul) {
  __shared__ unsigned short lA[128 * 64];
  __shared__ unsigned short lB[128 * 64];
  const int t = threadIdx.x;
  const int lane = t & 63;
  const int w = t >> 6;
  const int wr = w >> 1, wc = w & 1;
  const int r15 = lane & 15, g4 = lane >> 4;
  const int tileM = blockIdx.y * 128;
  const int tileN = blockIdx.x * 128;

  f32x4 acc[4][4];
  #pragma unroll
  for (int i = 0; i < 4; i++)
    #pragma unroll
    for (int j = 0; j < 4; j++) acc[i][j] = (f32x4){0.f, 0.f, 0.f, 0.f};

  const int nkt = K >> 6;
  for (int kt = 0; kt < nkt; ++kt) {
    const int k0 = kt * 64;
    #pragma unroll
    for (int i = 0; i < 4; ++i) {
      int flat = i * 256 + t;
      int row = flat >> 3, gc = flat & 7;            // [128 rows][8 granules of 8 bf16]
      unsigned lb = (unsigned)(i * 256 + w * 64) * 16; // wave-uniform LDS byte base
      gll16(A  + (size_t)(tileM + row) * K + k0 + gc * 8, (char*)lA + lb);
      gll16(Bt + (size_t)(tileN + row) * K + k0 + gc * 8, (char*)lB + lb);
    }
    __syncthreads();
    #pragma unroll
    for (int kk = 0; kk < 2; ++kk) {
      short8 af[4], bf[4];
      #pragma unroll
      for (int mt = 0; mt < 4; ++mt)
        af[mt] = *reinterpret_cast<const short8*>(&lA[(wr * 64 + mt * 16 + r15) * 64 + kk * 32 + g4 * 8]);
      #pragma unroll
      for (int nt = 0; nt < 4; ++nt)
        bf[nt] = *reinterpret_cast<const short8*>(&lB[(wc * 64 + nt * 16 + r15) * 64 + kk * 32 + g4 * 8]);
      #pragma unroll
      for (int mt = 0; mt < 4; ++mt)
        #pragma unroll
        for (int nt = 0; nt < 4; ++nt)
          acc[mt][nt] = __builtin_amdgcn_mfma_f32_16x16x32_bf16(af[mt], bf[nt], acc[mt][nt], 0, 0, 0);
    }
    __syncthreads();
  }

  // epilogue: C/D layout col=lane&15, row=(lane>>4)*4+reg
  #pragma unroll
  for (int mt = 0; mt < 4; ++mt) {
    #pragma unroll
    for (int nt = 0; nt < 4; ++nt) {
      int col = tileN + wc * 64 + nt * 16 + r15;
      #pragma unroll
      for (int r = 0; r < 4; ++r) {
        int row = tileM + wr * 64 + mt * 16 + g4 * 4 + r;
        float v = acc[mt][nt][r];
        if (MODE == 1) {
          ((float*)C)[(size_t)row * N + col] = v + b0[col];
        } else {
          if (col < 2048) {
            ((unsigned short*)C)[(size_t)row * 2048 + col] = f2bf((v + b0[col]) * cmul);
          } else if (col < 2176) {
            int dd = col - 2048;
            C2[(size_t)row * 128 + dd] = f2bf(v + b1[dd]);
          } else {
            int dd = col - 2176;
            int bb = row >> 11, s = row & 2047;
            C3[((size_t)bb * 128 + dd) * 2048 + s] = f2bf(v + b2[dd]);  // v^T [b][d][s]
          }
        }
      }
    }
  }
}

// ---------------- flash attention (MQA), swapped operands, exp2-direct ----------------
// grid (S/64, H, B), 256 threads = 4 waves; wave owns 16 q rows (q = r15 per lane).
// qb [B*S][2048] bf16 (pre-scaled by log2(e)/sqrt(d)), kb [B*S][128] bf16,
// vt [B][128][S] bf16, ob [B*S][2048] bf16
// QK^T = mfma(K,Q): D[kv][q]; softmax lane-local (q=r15); P=exp2(s'-m').
// PV  = mfma(V^T,P^T): D[d][q]; rescale lane-local.
// lP [q][kv] 8B granules swizzled g^r15; P/O packing via v_cvt_pk_bf16_f32.
__global__ __launch_bounds__(256)
void flash_mqa(const unsigned short* __restrict__ qb, const unsigned short* __restrict__ kb,
               const unsigned short* __restrict__ vt, unsigned short* __restrict__ ob) {
  __shared__ unsigned short lK[2][64 * 128];   // [kv][d], swizzled
  __shared__ unsigned short lV[2][128 * 64];   // [d][kv], swizzled
  __shared__ unsigned short lP[4][16 * 64];    // per-wave [q][kv], granule-swizzled

  const int t = threadIdx.x;
  const int lane = t & 63;
  const int w = t >> 6;
  const int r15 = lane & 15, g4 = lane >> 4;
  const int qt = blockIdx.x, h = blockIdx.y, b = blockIdx.z;
  const int q0 = qt * 64 + w * 16;

  // persistent Q B-frags (layout identical to A-frag): row q=r15, k = g4*8
  short8 qf[4];
  const size_t qrow = (size_t)(b * 2048 + q0 + r15);
  #pragma unroll
  for (int kk = 0; kk < 4; ++kk)
    qf[kk] = *reinterpret_cast<const short8*>(&qb[qrow * 2048 + h * 128 + kk * 32 + g4 * 8]);

  f32x4 oacc[8];   // O^T: oacc[ot][r] -> d = ot*16+g4*4+r, q = r15
  #pragma unroll
  for (int i = 0; i < 8; i++) oacc[i] = (f32x4){0.f, 0.f, 0.f, 0.f};
  float m_q = -1e30f, l_q = 0.f;   // per-lane: one q row (log2 units)

  const unsigned short* kbase = kb + (size_t)b * 2048 * 128;
  const unsigned short* vbase = vt + (size_t)b * 128 * 2048;

  auto stage = [&](int buf, int kv0) {
    #pragma unroll
    for (int i = 0; i < 4; ++i) {
      int flat = i * 256 + t;
      unsigned lb = (unsigned)(i * 256 + w * 64) * 16;
      { int row = flat >> 4, gc = flat & 15;
        gll16(kbase + (size_t)(kv0 + row) * 128 + ((gc ^ (row & 15)) << 3), (char*)lK[buf] + lb); }
      { int row = flat >> 3, gc = flat & 7;
        gll16(vbase + (size_t)row * 2048 + kv0 + ((gc ^ (row & 7)) << 3), (char*)lV[buf] + lb); }
    }
  };

  stage(0, 0);
  int cur = 0;
  for (int it = 0; it < 32; ++it) {
    if (it < 31) {
      stage(cur ^ 1, (it + 1) * 64);
      asm volatile("s_waitcnt vmcnt(8)" ::: "memory");  // current tile's 8 loads done
    } else {
      asm volatile("s_waitcnt vmcnt(0)" ::: "memory");
    }
    __builtin_amdgcn_s_barrier();
    asm volatile("" ::: "memory");

    const unsigned short* cK = lK[cur];
    const unsigned short* cV = lV[cur];

    // ---- QK^T swapped: s[ct] = K_sub(ct) x Q -> D[kv][q] (log2-scaled) ----
    f32x4 s[4];
    #pragma unroll
    for (int ct = 0; ct < 4; ct++) s[ct] = (f32x4){0.f, 0.f, 0.f, 0.f};
    #pragma unroll
    for (int kk = 0; kk < 4; ++kk) {
      #pragma unroll
      for (int ct = 0; ct < 4; ++ct) {
        const int krow = ct * 16 + r15;
        const int kg = (kk * 4 + g4) ^ (krow & 15);
        short8 kf = *reinterpret_cast<const short8*>(&cK[krow * 128 + kg * 8]);
        s[ct] = __builtin_amdgcn_mfma_f32_16x16x32_bf16(kf, qf[kk], s[ct], 0, 0, 0);
      }
    }

    // ---- softmax: lane owns q=r15 with 16 kv values ----
    float mx = s[0][0];
    #pragma unroll
    for (int ct = 0; ct < 4; ++ct)
      #pragma unroll
      for (int r = 0; r < 4; ++r) mx = fmaxf(mx, s[ct][r]);
    mx = fmaxf(mx, __shfl_xor(mx, 16));
    mx = fmaxf(mx, __shfl_xor(mx, 32));
    // T13 defer-max: rescale only when growth > 8/ln2 (P bounded by e^8)
    if (__any(mx > m_q + 11.5416f)) {
      float mn = fmaxf(m_q, mx);
      float rf = exp2f(m_q - mn);   // lane-local (q=r15)
      m_q = mn;
      l_q *= rf;
      #pragma unroll
      for (int ot = 0; ot < 8; ++ot)
        #pragma unroll
        for (int r = 0; r < 4; ++r) oacc[ot][r] *= rf;
    }
    // ---- P = exp2(s-m), cvt_pk pack, b64 write to lP (granule ^ r15) ----
    #pragma unroll
    for (int ct = 0; ct < 4; ++ct) {
      float p0 = exp2f(s[ct][0] - m_q);
      float p1 = exp2f(s[ct][1] - m_q);
      float p2 = exp2f(s[ct][2] - m_q);
      float p3 = exp2f(s[ct][3] - m_q);
      l_q += (p0 + p1) + (p2 + p3);
      const int gi = (ct * 4 + g4) ^ r15;
      *reinterpret_cast<uint2*>(&lP[w][r15 * 64 + gi * 4]) = make_uint2(pkc(p0, p1), pkc(p2, p3));
    }

    // ---- PV swapped: oacc = V^T_sub(ot) x P^T -> D[d][q] ----
    #pragma unroll
    for (int kk = 0; kk < 2; ++kk) {
      const int gA = (kk * 8 + g4 * 2) ^ r15;
      const int gB = (kk * 8 + g4 * 2 + 1) ^ r15;
      const uint2 wa = *reinterpret_cast<const uint2*>(&lP[w][r15 * 64 + gA * 4]);
      const uint2 wb = *reinterpret_cast<const uint2*>(&lP[w][r15 * 64 + gB * 4]);
      uint4v pw = {wa.x, wa.y, wb.x, wb.y};
      short8 pf = __builtin_bit_cast(short8, pw);
      #pragma unroll
      for (int ot = 0; ot < 8; ++ot) {
        const int vrow = ot * 16 + r15;
        const int vg = (kk * 4 + g4) ^ (vrow & 7);
        short8 vf = *reinterpret_cast<const short8*>(&cV[vrow * 64 + vg * 8]);
        oacc[ot] = __builtin_amdgcn_mfma_f32_16x16x32_bf16(vf, pf, oacc[ot], 0, 0, 0);
      }
    }

    asm volatile("" ::: "memory");
    __builtin_amdgcn_s_barrier();   // all waves done reading buf[cur] before restage
    cur ^= 1;
  }

  // epilogue: cross-lane l reduce (kv partials live on lanes r15, r15+16, +32, +48)
  float l = l_q;
  l += __shfl_xor(l, 16);
  l += __shfl_xor(l, 32);
  const float inv = 1.0f / l;
  const int row = q0 + r15;
  const size_t base = ((size_t)(b * 2048 + row)) * 2048 + h * 128;
  #pragma unroll
  for (int ot = 0; ot < 8; ++ot) {
    uint2 pw = make_uint2(pkc(oacc[ot][0] * inv, oacc[ot][1] * inv),
                          pkc(oacc[ot][2] * inv, oacc[ot][3] * inv));
    *reinterpret_cast<uint2*>(&ob[base + ot * 16 + g4 * 4]) = pw;
  }
}

extern "C" void kernel_launch(void* const* d_in, const int* in_sizes, int n_in,
                              void* d_out, int out_size, void* d_ws, size_t ws_size,
                              hipStream_t stream) {
  const float* x  = (const float*)d_in[0];
  const float* Wq = (const float*)d_in[1];
  const float* bq = (const float*)d_in[2];
  const float* Wk = (const float*)d_in[3];
  const float* bk = (const float*)d_in[4];
  const float* Wv = (const float*)d_in[5];
  const float* bv = (const float*)d_in[6];
  const float* Wo = (const float*)d_in[7];
  const float* bo = (const float*)d_in[8];
  float* out = (float*)d_out;

  char* ws = (char*)d_ws;
  size_t off = 0;
  auto alloc = [&](size_t elems) {
    unsigned short* p = (unsigned short*)(ws + off);
    off += (elems * 2 + 255) & ~(size_t)255;
    return p;
  };
  unsigned short* xb    = alloc(8388608);   // x bf16 [4096][2048]
  unsigned short* qb    = alloc(8388608);   // q bf16 [4096][2048] (pre-scaled, log2 units)
  unsigned short* ob    = alloc(8388608);   // attn out bf16 [4096][2048]
  unsigned short* wqkvt = alloc(4718592);   // [Wq^T;Wk^T;Wv^T] [2304][2048]
  unsigned short* wot   = alloc(4194304);   // Wo^T [2048][2048]
  unsigned short* kbuf  = alloc(524288);    // k bf16 [4096][128]
  unsigned short* vtb   = alloc(524288);    // v^T bf16 [2][128][2048]

  // 1/sqrt(128) * log2(e): scores come out of QK^T already in log2 units
  const float qscale = 0.08838834764831845f * 1.44269504088896f;

  dim3 tb(32, 8);
  cvtk<<<4096, 256, 0, stream>>>(x, xb, 2097152);
  tcvt2<<<dim3(64, 64, 2), tb, 0, stream>>>(Wq, Wo, wqkvt, wot, 2048, 2048);
  tcvt2<<<dim3(4, 64, 2),  tb, 0, stream>>>(Wk, Wv, wqkvt + (size_t)2048 * 2048,
                                            wqkvt + (size_t)2176 * 2048, 2048, 128);

  gemm_nt<3><<<dim3(18, 32), 256, 0, stream>>>(xb, wqkvt, bq, bk, bv,
                                               qb, kbuf, vtb, 4096, 2304, 2048, qscale);
  flash_mqa<<<dim3(32, 16, 2), 256, 0, stream>>>(qb, kbuf, vtb, ob);
  gemm_nt<1><<<dim3(16, 32), 256, 0, stream>>>(ob, wot, bo, nullptr, nullptr,
                                               out, nullptr, nullptr, 4096, 2048, 2048, 1.0f);
}

// Round 9
// 286.953 us; speedup vs baseline: 1.0204x; 1.0204x over previous
//
#include <hip/hip_runtime.h>

// MQA forward on MI355X (gfx950), bf16 MFMA path.
// B=2, S=2048, D_MODEL=2048, H=16, HEAD_DIM=128 (MQA: K/V shared across heads).
// R2: T2 XOR-swizzle in flash (bank conflicts 9.1e7 -> 0; 290 -> 191 us).
// R4: 2-phase dbuf staging (vmcnt(8)): -2%. Kept.
// R5: direct-global K/V frags: -87% (uncoalesced gather). REVERTED.
// R6: softmax-lite (deferred l-sum, T13 defer-max): 187 -> 167 us.
// R7: swapped-operand flash (lane owns one q-row): 167 -> 139 us.
// R8: cvt_pk inline asm: -2.6% (m240 confirmed: asm defeats scheduler). REVERTED.
//     exp2-direct (log2e folded into Q scale): kept.
// R9: 2 heads per block (MQA K/V shared): staging+barriers amortized 2x;
//     grid 1024 -> 512 (exactly 2 blocks/CU).

typedef __attribute__((ext_vector_type(8))) short short8;
typedef __attribute__((ext_vector_type(4))) float f32x4;
typedef __attribute__((ext_vector_type(4))) unsigned int uint4v;

__device__ __forceinline__ unsigned short f2bf(float f) {
  unsigned int u = __float_as_uint(f);
  u += 0x7FFF + ((u >> 16) & 1);   // RNE
  return (unsigned short)(u >> 16);
}

__device__ __forceinline__ unsigned int pk2(float a, float b) {
  return (unsigned int)f2bf(a) | ((unsigned int)f2bf(b) << 16);
}

// async global->LDS 16B: dst must be wave-uniform (HW adds lane*16)
__device__ __forceinline__ void gll16(const void* g, void* lds) {
  __builtin_amdgcn_global_load_lds(
      (const __attribute__((address_space(1))) unsigned int*)g,
      (__attribute__((address_space(3))) unsigned int*)lds, 16, 0, 0);
}

// ---------------- elementwise f32 -> bf16 ----------------
__global__ __launch_bounds__(256) void cvtk(const float* __restrict__ in,
                                            unsigned short* __restrict__ out, int n4) {
  int i = blockIdx.x * blockDim.x + threadIdx.x;
  int stride = gridDim.x * blockDim.x;
  for (; i < n4; i += stride) {
    float4 v = reinterpret_cast<const float4*>(in)[i];
    ushort4 o;
    o.x = f2bf(v.x); o.y = f2bf(v.y); o.z = f2bf(v.z); o.w = f2bf(v.w);
    reinterpret_cast<ushort4*>(out)[i] = o;
  }
}

// ------- transpose + convert (paired): W[K][N] f32 -> Wt[N][K] bf16, z selects -------
__global__ __launch_bounds__(256) void tcvt2(const float* __restrict__ W0, const float* __restrict__ W1,
                                             unsigned short* __restrict__ D0, unsigned short* __restrict__ D1,
                                             int K, int N) {
  const float* W = blockIdx.z ? W1 : W0;
  unsigned short* Wt = blockIdx.z ? D1 : D0;
  __shared__ float tile[32][33];
  int n0 = blockIdx.x * 32, k0 = blockIdx.y * 32;
  int tx = threadIdx.x, ty = threadIdx.y;
  #pragma unroll
  for (int i = 0; i < 32; i += 8)
    tile[ty + i][tx] = W[(size_t)(k0 + ty + i) * N + n0 + tx];
  __syncthreads();
  #pragma unroll
  for (int i = 0; i < 32; i += 8)
    Wt[(size_t)(n0 + ty + i) * K + k0 + tx] = f2bf(tile[tx][ty + i]);
}

// ---------------- GEMM: C = A[M][K] @ Bt[N][K]^T + bias ----------------
// 128x128 tile, BK=64, 256 threads = 4 waves (2x2 of 64x64), m97-style.
// MODE 1: f32 out C[M][N] (+b0)
// MODE 3: fused QKV epilogue (N=2304):
//   col<2048   -> qb[row][col] bf16 = (acc+b0)*cmul
//   col<2176   -> kbuf[row][col-2048] bf16 (+b1)
//   else       -> vt[b][col-2176][s] bf16 (+b2), transposed
template <int MODE>
__global__ __launch_bounds__(256)
void gemm_nt(const unsigned short* __restrict__ A, const unsigned short* __restrict__ Bt,
             const float* __restrict__ b0, const float* __restrict__ b1,
             const float* __restrict__ b2,
             void* __restrict__ C, unsigned short* __restrict__ C2,
             unsigned short* __restrict__ C3, int M, int N, int K, float cmul) {
  __shared__ unsigned short lA[128 * 64];
  __shared__ unsigned short lB[128 * 64];
  const int t = threadIdx.x;
  const int lane = t & 63;
  const int w = t >> 6;
  const int wr = w >> 1, wc = w & 1;
  const int r15 = lane & 15, g4 = lane >> 4;
  const int tileM = blockIdx.y * 128;
  const int tileN = blockIdx.x * 128;

  f32x4 acc[4][4];
  #pragma unroll
  for (int i = 0; i < 4; i++)
    #pragma unroll
    for (int j = 0; j < 4; j++) acc[i][j] = (f32x4){0.f, 0.f, 0.f, 0.f};

  const int nkt = K >> 6;
  for (int kt = 0; kt < nkt; ++kt) {
    const int k0 = kt * 64;
    #pragma unroll
    for (int i = 0; i < 4; ++i) {
      int flat = i * 256 + t;
      int row = flat >> 3, gc = flat & 7;            // [128 rows][8 granules of 8 bf16]
      unsigned lb = (unsigned)(i * 256 + w * 64) * 16; // wave-uniform LDS byte base
      gll16(A  + (size_t)(tileM + row) * K + k0 + gc * 8, (char*)lA + lb);
      gll16(Bt + (size_t)(tileN + row) * K + k0 + gc * 8, (char*)lB + lb);
    }
    __syncthreads();
    #pragma unroll
    for (int kk = 0; kk < 2; ++kk) {
      short8 af[4], bf[4];
      #pragma unroll
      for (int mt = 0; mt < 4; ++mt)
        af[mt] = *reinterpret_cast<const short8*>(&lA[(wr * 64 + mt * 16 + r15) * 64 + kk * 32 + g4 * 8]);
      #pragma unroll
      for (int nt = 0; nt < 4; ++nt)
        bf[nt] = *reinterpret_cast<const short8*>(&lB[(wc * 64 + nt * 16 + r15) * 64 + kk * 32 + g4 * 8]);
      #pragma unroll
      for (int mt = 0; mt < 4; ++mt)
        #pragma unroll
        for (int nt = 0; nt < 4; ++nt)
          acc[mt][nt] = __builtin_amdgcn_mfma_f32_16x16x32_bf16(af[mt], bf[nt], acc[mt][nt], 0, 0, 0);
    }
    __syncthreads();
  }

  // epilogue: C/D layout col=lane&15, row=(lane>>4)*4+reg
  #pragma unroll
  for (int mt = 0; mt < 4; ++mt) {
    #pragma unroll
    for (int nt = 0; nt < 4; ++nt) {
      int col = tileN + wc * 64 + nt * 16 + r15;
      #pragma unroll
      for (int r = 0; r < 4; ++r) {
        int row = tileM + wr * 64 + mt * 16 + g4 * 4 + r;
        float v = acc[mt][nt][r];
        if (MODE == 1) {
          ((float*)C)[(size_t)row * N + col] = v + b0[col];
        } else {
          if (col < 2048) {
            ((unsigned short*)C)[(size_t)row * 2048 + col] = f2bf((v + b0[col]) * cmul);
          } else if (col < 2176) {
            int dd = col - 2048;
            C2[(size_t)row * 128 + dd] = f2bf(v + b1[dd]);
          } else {
            int dd = col - 2176;
            int bb = row >> 11, s = row & 2047;
            C3[((size_t)bb * 128 + dd) * 2048 + s] = f2bf(v + b2[dd]);  // v^T [b][d][s]
          }
        }
      }
    }
  }
}

// ---------------- flash attention (MQA), swapped operands, 2 heads/block ----------------
// grid (S/64, H/2, B), 256 threads = 4 waves; wave owns 16 q rows (q = r15 per lane).
// qb [B*S][2048] bf16 (pre-scaled by log2(e)/sqrt(d)), kb [B*S][128] bf16,
// vt [B][128][S] bf16, ob [B*S][2048] bf16
// QK^T = mfma(K,Q): D[kv][q]; softmax lane-local (q=r15); P=exp2(s'-m').
// PV  = mfma(V^T,P^T): D[d][q]; rescale lane-local.
// 2 heads share the staged K/V tile (MQA) -> stage/barrier cost amortized 2x.
// lP [q][kv] 8B granules swizzled g^r15, reused sequentially per head
// (per-wave in-order DS pipeline).
__global__ __launch_bounds__(256)
void flash_mqa(const unsigned short* __restrict__ qb, const unsigned short* __restrict__ kb,
               const unsigned short* __restrict__ vt, unsigned short* __restrict__ ob) {
  __shared__ unsigned short lK[2][64 * 128];   // [kv][d], swizzled
  __shared__ unsigned short lV[2][128 * 64];   // [d][kv], swizzled
  __shared__ unsigned short lP[4][16 * 64];    // per-wave [q][kv], granule-swizzled

  const int t = threadIdx.x;
  const int lane = t & 63;
  const int w = t >> 6;
  const int r15 = lane & 15, g4 = lane >> 4;
  const int qt = blockIdx.x, hy = blockIdx.y, b = blockIdx.z;
  const int q0 = qt * 64 + w * 16;

  // persistent Q B-frags for 2 heads: row q=r15, k = g4*8
  short8 qf[2][4];
  const size_t qrow = (size_t)(b * 2048 + q0 + r15);
  #pragma unroll
  for (int hh = 0; hh < 2; ++hh)
    #pragma unroll
    for (int kk = 0; kk < 4; ++kk)
      qf[hh][kk] = *reinterpret_cast<const short8*>(
          &qb[qrow * 2048 + (hy * 2 + hh) * 128 + kk * 32 + g4 * 8]);

  f32x4 oacc[2][8];   // O^T: oacc[hh][ot][r] -> d = ot*16+g4*4+r, q = r15
  #pragma unroll
  for (int hh = 0; hh < 2; ++hh)
    #pragma unroll
    for (int i = 0; i < 8; i++) oacc[hh][i] = (f32x4){0.f, 0.f, 0.f, 0.f};
  float m_q[2] = {-1e30f, -1e30f}, l_q[2] = {0.f, 0.f};  // log2 units

  const unsigned short* kbase = kb + (size_t)b * 2048 * 128;
  const unsigned short* vbase = vt + (size_t)b * 128 * 2048;

  auto stage = [&](int buf, int kv0) {
    #pragma unroll
    for (int i = 0; i < 4; ++i) {
      int flat = i * 256 + t;
      unsigned lb = (unsigned)(i * 256 + w * 64) * 16;
      { int row = flat >> 4, gc = flat & 15;
        gll16(kbase + (size_t)(kv0 + row) * 128 + ((gc ^ (row & 15)) << 3), (char*)lK[buf] + lb); }
      { int row = flat >> 3, gc = flat & 7;
        gll16(vbase + (size_t)row * 2048 + kv0 + ((gc ^ (row & 7)) << 3), (char*)lV[buf] + lb); }
    }
  };

  stage(0, 0);
  int cur = 0;
  for (int it = 0; it < 32; ++it) {
    if (it < 31) {
      stage(cur ^ 1, (it + 1) * 64);
      asm volatile("s_waitcnt vmcnt(8)" ::: "memory");  // current tile's 8 loads done
    } else {
      asm volatile("s_waitcnt vmcnt(0)" ::: "memory");
    }
    __builtin_amdgcn_s_barrier();
    asm volatile("" ::: "memory");

    const unsigned short* cK = lK[cur];
    const unsigned short* cV = lV[cur];

    #pragma unroll
    for (int hh = 0; hh < 2; ++hh) {
      // ---- QK^T swapped: s[ct] = K_sub(ct) x Q -> D[kv][q] (log2-scaled) ----
      f32x4 s[4];
      #pragma unroll
      for (int ct = 0; ct < 4; ct++) s[ct] = (f32x4){0.f, 0.f, 0.f, 0.f};
      #pragma unroll
      for (int kk = 0; kk < 4; ++kk) {
        #pragma unroll
        for (int ct = 0; ct < 4; ++ct) {
          const int krow = ct * 16 + r15;
          const int kg = (kk * 4 + g4) ^ (krow & 15);
          short8 kf = *reinterpret_cast<const short8*>(&cK[krow * 128 + kg * 8]);
          s[ct] = __builtin_amdgcn_mfma_f32_16x16x32_bf16(kf, qf[hh][kk], s[ct], 0, 0, 0);
        }
      }

      // ---- softmax: lane owns q=r15 with 16 kv values ----
      float mx = s[0][0];
      #pragma unroll
      for (int ct = 0; ct < 4; ++ct)
        #pragma unroll
        for (int r = 0; r < 4; ++r) mx = fmaxf(mx, s[ct][r]);
      mx = fmaxf(mx, __shfl_xor(mx, 16));
      mx = fmaxf(mx, __shfl_xor(mx, 32));
      // T13 defer-max: rescale only when growth > 8/ln2 (P bounded by e^8)
      if (__any(mx > m_q[hh] + 11.5416f)) {
        float mn = fmaxf(m_q[hh], mx);
        float rf = exp2f(m_q[hh] - mn);   // lane-local (q=r15)
        m_q[hh] = mn;
        l_q[hh] *= rf;
        #pragma unroll
        for (int ot = 0; ot < 8; ++ot)
          #pragma unroll
          for (int r = 0; r < 4; ++r) oacc[hh][ot][r] *= rf;
      }
      // ---- P = exp2(s-m), pack, b64 write to lP (granule ^ r15) ----
      #pragma unroll
      for (int ct = 0; ct < 4; ++ct) {
        float p0 = exp2f(s[ct][0] - m_q[hh]);
        float p1 = exp2f(s[ct][1] - m_q[hh]);
        float p2 = exp2f(s[ct][2] - m_q[hh]);
        float p3 = exp2f(s[ct][3] - m_q[hh]);
        l_q[hh] += (p0 + p1) + (p2 + p3);
        const int gi = (ct * 4 + g4) ^ r15;
        *reinterpret_cast<uint2*>(&lP[w][r15 * 64 + gi * 4]) = make_uint2(pk2(p0, p1), pk2(p2, p3));
      }

      // ---- PV swapped: oacc = V^T_sub(ot) x P^T -> D[d][q] ----
      #pragma unroll
      for (int kk = 0; kk < 2; ++kk) {
        const int gA = (kk * 8 + g4 * 2) ^ r15;
        const int gB = (kk * 8 + g4 * 2 + 1) ^ r15;
        const uint2 wa = *reinterpret_cast<const uint2*>(&lP[w][r15 * 64 + gA * 4]);
        const uint2 wb = *reinterpret_cast<const uint2*>(&lP[w][r15 * 64 + gB * 4]);
        uint4v pw = {wa.x, wa.y, wb.x, wb.y};
        short8 pf = __builtin_bit_cast(short8, pw);
        #pragma unroll
        for (int ot = 0; ot < 8; ++ot) {
          const int vrow = ot * 16 + r15;
          const int vg = (kk * 4 + g4) ^ (vrow & 7);
          short8 vf = *reinterpret_cast<const short8*>(&cV[vrow * 64 + vg * 8]);
          oacc[hh][ot] = __builtin_amdgcn_mfma_f32_16x16x32_bf16(vf, pf, oacc[hh][ot], 0, 0, 0);
        }
      }
    }

    asm volatile("" ::: "memory");
    __builtin_amdgcn_s_barrier();   // all waves done reading buf[cur] before restage
    cur ^= 1;
  }

  // epilogue: cross-lane l reduce (kv partials live on lanes r15, r15+16, +32, +48)
  #pragma unroll
  for (int hh = 0; hh < 2; ++hh) {
    float l = l_q[hh];
    l += __shfl_xor(l, 16);
    l += __shfl_xor(l, 32);
    const float inv = 1.0f / l;
    const int row = q0 + r15;
    const size_t base = ((size_t)(b * 2048 + row)) * 2048 + (hy * 2 + hh) * 128;
    #pragma unroll
    for (int ot = 0; ot < 8; ++ot) {
      uint2 pw = make_uint2(pk2(oacc[hh][ot][0] * inv, oacc[hh][ot][1] * inv),
                            pk2(oacc[hh][ot][2] * inv, oacc[hh][ot][3] * inv));
      *reinterpret_cast<uint2*>(&ob[base + ot * 16 + g4 * 4]) = pw;
    }
  }
}

extern "C" void kernel_launch(void* const* d_in, const int* in_sizes, int n_in,
                              void* d_out, int out_size, void* d_ws, size_t ws_size,
                              hipStream_t stream) {
  const float* x  = (const float*)d_in[0];
  const float* Wq = (const float*)d_in[1];
  const float* bq = (const float*)d_in[2];
  const float* Wk = (const float*)d_in[3];
  const float* bk = (const float*)d_in[4];
  const float* Wv = (const float*)d_in[5];
  const float* bv = (const float*)d_in[6];
  const float* Wo = (const float*)d_in[7];
  const float* bo = (const float*)d_in[8];
  float* out = (float*)d_out;

  char* ws = (char*)d_ws;
  size_t off = 0;
  auto alloc = [&](size_t elems) {
    unsigned short* p = (unsigned short*)(ws + off);
    off += (elems * 2 + 255) & ~(size_t)255;
    return p;
  };
  unsigned short* xb    = alloc(8388608);   // x bf16 [4096][2048]
  unsigned short* qb    = alloc(8388608);   // q bf16 [4096][2048] (pre-scaled, log2 units)
  unsigned short* ob    = alloc(8388608);   // attn out bf16 [4096][2048]
  unsigned short* wqkvt = alloc(4718592);   // [Wq^T;Wk^T;Wv^T] [2304][2048]
  unsigned short* wot   = alloc(4194304);   // Wo^T [2048][2048]
  unsigned short* kbuf  = alloc(524288);    // k bf16 [4096][128]
  unsigned short* vtb   = alloc(524288);    // v^T bf16 [2][128][2048]

  // 1/sqrt(128) * log2(e): scores come out of QK^T already in log2 units
  const float qscale = 0.08838834764831845f * 1.44269504088896f;

  dim3 tb(32, 8);
  cvtk<<<4096, 256, 0, stream>>>(x, xb, 2097152);
  tcvt2<<<dim3(64, 64, 2), tb, 0, stream>>>(Wq, Wo, wqkvt, wot, 2048, 2048);
  tcvt2<<<dim3(4, 64, 2),  tb, 0, stream>>>(Wk, Wv, wqkvt + (size_t)2048 * 2048,
                                            wqkvt + (size_t)2176 * 2048, 2048, 128);

  gemm_nt<3><<<dim3(18, 32), 256, 0, stream>>>(xb, wqkvt, bq, bk, bv,
                                               qb, kbuf, vtb, 4096, 2304, 2048, qscale);
  flash_mqa<<<dim3(32, 8, 2), 256, 0, stream>>>(qb, kbuf, vtb, ob);
  gemm_nt<1><<<dim3(16, 32), 256, 0, stream>>>(ob, wot, bo, nullptr, nullptr,
                                               out, nullptr, nullptr, 4096, 2048, 2048, 1.0f);
}